// Round 3
// baseline (11.629 us; speedup 1.0000x reference)
//
#include <hip/hip_runtime.h>
#include <math.h>

#define UNITS 128
#define THETA 4.0f
#define MDEG  16

// out_b = x_b @ expm(t_b * K)  ==  expm(t_b * K^T) @ x_b
// K tridiagonal: K[i][i]=sigma[i], K[i][i+1]=ceta[i], K[i+1][i]=-ceta[i]
//
// One wave handles TWO batch elements (ILP-2 hides shuffle latency);
// lane l owns rows 2l, 2l+1 of both.
//
// Spectral shift: expm(A)x = e^mu * expm(A - mu*I)x with mu = t*(U+L)/2,
// [L,U] = span of Gershgorin intervals of K. Shrinks ||A-mu*I||_inf from
// t*max(|sig|+rho) (~10t) to t*(U-L)/2 (~7t) -> fewer sub-steps.
// s = ceil(r/THETA) sub-steps, degree-MDEG Taylor each, e^{mu/s} folded per
// step so intermediates stay bounded (growth e^{(U-L)t/2s} <= e^2.7 before
// the fold). Truncation <= THETA^(M+1)/(M+1)! ~ 5e-5 per step.

__global__ __launch_bounds__(256) void expv_kernel(
    const float* __restrict__ inputs,   // [B, UNITS+1]
    const float* __restrict__ params,   // [2*UNITS-1]
    float* __restrict__ out,            // [B, UNITS]
    int B)
{
    const int gid  = blockIdx.x * blockDim.x + threadIdx.x;
    const int wave = gid >> 6;
    const int lane = gid & 63;
    const int eA   = wave * 2;
    if (eA >= B) return;
    const int  eB   = eA + 1;
    const bool hasB = (eB < B);

    const int i0 = lane * 2;

    // ---- batch-independent K coefficients ----
    const float p0 = params[i0];
    const float p1 = params[i0 + 1];
    const float sp0 = fmaxf(p0, 0.f) + log1pf(expf(-fabsf(p0)));  // stable softplus
    const float sp1 = fmaxf(p1, 0.f) + log1pf(expf(-fabsf(p1)));
    const float sig0 = -sp0 * sp0;                                 // sigma[2l]
    const float sig1 = -sp1 * sp1;                                 // sigma[2l+1]
    const float ce0 = -params[UNITS + i0];                         // ceta[2l]
    const float ce1 = (lane < 63) ? -params[UNITS + i0 + 1] : 0.f; // ceta[2l+1]
    const float ced = (lane > 0)  ? -params[UNITS + i0 - 1] : 0.f; // ceta[2l-1]

    // Gershgorin span of K: row i -> [sig_i - rho_i, sig_i + rho_i]
    const float rho0 = fabsf(ce0) + fabsf(ced);
    const float rho1 = fabsf(ce1) + fabsf(ce0);
    float U = fmaxf(sig0 + rho0, sig1 + rho1);
    float L = fminf(sig0 - rho0, sig1 - rho1);
    #pragma unroll
    for (int off = 32; off >= 1; off >>= 1) {
        U = fmaxf(U, __shfl_xor(U, off, 64));
        L = fminf(L, __shfl_xor(L, off, 64));
    }
    const float cshift = 0.5f * (U + L);   // shift center (negative)
    const float rad    = 0.5f * (U - L);   // shifted inf-norm bound of K

    // ---- per-element data ----
    const float* rowA = inputs + (size_t)eA * (UNITS + 1);
    const float* rowB = inputs + (size_t)(hasB ? eB : eA) * (UNITS + 1);
    const float x0A = rowA[i0], x1A = rowA[i0 + 1], tA = rowA[UNITS];
    const float x0B = rowB[i0], x1B = rowB[i0 + 1], tB = rowB[UNITS];

    // shared sub-step count from the larger shifted norm
    const float r = rad * fmaxf(tA, tB);
    int s = (int)ceilf(r / THETA);
    s = (s < 1) ? 1 : ((s > 32) ? 32 : s);
    const float inv_s = 1.0f / (float)s;

    // pre-scaled shifted tridiagonal coefficients of (A - mu I)/s per element
    const float fA = tA * inv_s, fB = tB * inv_s;
    const float a0A = (sig0 - cshift) * fA, a1A = (sig1 - cshift) * fA;
    const float c0A = ce0 * fA,  c1A = ce1 * fA,  cdA = ced * fA;
    const float a0B = (sig0 - cshift) * fB, a1B = (sig1 - cshift) * fB;
    const float c0B = ce0 * fB,  c1B = ce1 * fB,  cdB = ced * fB;
    const float gA = expf(cshift * fA);    // e^{mu_A/s} <= 1
    const float gB = expf(cshift * fB);

    // w = ( e^{mu/s} * Taylor_MDEG((A-mu I)/s) )^s x, two chains interleaved
    float w0A = x0A, w1A = x1A;
    float w0B = x0B, w1B = x1B;
    for (int step = 0; step < s; ++step) {
        float q0A = w0A, q1A = w1A, acc0A = w0A, acc1A = w1A;
        float q0B = w0B, q1B = w1B, acc0B = w0B, acc1B = w1B;
        #pragma unroll
        for (int k = 1; k <= MDEG; ++k) {
            const float dA = __shfl_up  (q1A, 1, 64);  // w[2l-1] (lane0 garbage, cd=0)
            const float uA = __shfl_down(q0A, 1, 64);  // w[2l+2] (lane63 garbage, c1=0)
            const float dB = __shfl_up  (q1B, 1, 64);
            const float uB = __shfl_down(q0B, 1, 64);
            const float ck = 1.0f / (float)k;          // folds to constant under unroll
            const float n0A = (a0A * q0A - c0A * q1A + cdA * dA) * ck;
            const float n1A = (a1A * q1A - c1A * uA  + c0A * q0A) * ck;
            const float n0B = (a0B * q0B - c0B * q1B + cdB * dB) * ck;
            const float n1B = (a1B * q1B - c1B * uB  + c0B * q0B) * ck;
            q0A = n0A; q1A = n1A; acc0A += q0A; acc1A += q1A;
            q0B = n0B; q1B = n1B; acc0B += q0B; acc1B += q1B;
        }
        w0A = acc0A * gA; w1A = acc1A * gA;
        w0B = acc0B * gB; w1B = acc1B * gB;
    }

    // coalesced float2 stores (row offset = e*512 B, 8-aligned)
    float2* orA = (float2*)(out + (size_t)eA * UNITS);
    orA[lane] = make_float2(w0A, w1A);
    if (hasB) {
        float2* orB = (float2*)(out + (size_t)eB * UNITS);
        orB[lane] = make_float2(w0B, w1B);
    }
}

extern "C" void kernel_launch(void* const* d_in, const int* in_sizes, int n_in,
                              void* d_out, int out_size, void* d_ws, size_t ws_size,
                              hipStream_t stream) {
    const float* inputs = (const float*)d_in[0];
    const float* params = (const float*)d_in[1];
    float* out = (float*)d_out;

    const int B = in_sizes[0] / (UNITS + 1);        // 4096
    const int n_waves = (B + 1) / 2;                // 2 elements per wave
    const int waves_per_block = 4;                  // 256 threads
    const int grid = (n_waves + waves_per_block - 1) / waves_per_block;

    expv_kernel<<<grid, 64 * waves_per_block, 0, stream>>>(inputs, params, out, B);
}